// Round 9
// baseline (325.612 us; speedup 1.0000x reference)
//
#include <hip/hip_runtime.h>
#include <cstddef>
#include <cstdint>

constexpr int LSEQ = 4096;
constexpr int DM   = 1024;
constexpr int HD   = 64;
constexpr int BHT  = 32;     // B*H
constexpr int TOPU = 819;
constexpr int MROWS = 8192;  // B*L
constexpr int NSEG = 4;      // attention split-K segments

typedef unsigned short u16;
typedef __attribute__((ext_vector_type(8))) short short8v;     // 8 bf16
typedef __attribute__((ext_vector_type(4))) short short4v;     // 4 bf16
typedef __attribute__((ext_vector_type(8))) _Float16 half8v;   // 8 fp16
typedef __attribute__((ext_vector_type(4))) float f32x4;

__device__ __forceinline__ u16 f2bf(float f) {
  uint32_t u = __float_as_uint(f);
  u += 0x7fffu + ((u >> 16) & 1u);   // RNE
  return (u16)(u >> 16);
}
__device__ __forceinline__ float bf2f(u16 h) {
  return __uint_as_float(((uint32_t)h) << 16);
}

// async 16B global -> LDS (DMA).  LDS dest wave-uniform base; HW adds lane*16.
__device__ __forceinline__ void gl16(const void* g, void* l) {
  __builtin_amdgcn_global_load_lds(
      (const __attribute__((address_space(1))) void*)g,
      (__attribute__((address_space(3))) void*)l, 16, 0, 0);
}

// Inverse of the LDS swizzle e = (R*32 + C*8) ^ ((R&7)<<3) for linear slot S.
__device__ __forceinline__ void inv_swz(int S, int& R, int& C) {
  const int R0 = ((S >> 5) ^ (S >> 7)) & 1;
  const int R1 = (S >> 6) & 1;
  R = ((S >> 6) << 1) | R0;
  C = (((S >> 3) & 1) ^ R0) | ((((S >> 4) & 1) ^ R1) << 1);
}

// ---------------------------------------------------------------------------
// Fused prep: x -> {fp16 hi, fp16 lo(x256), bf16}; Wq -> fp16 2-piece;
// Wk/Wv/Wo -> bf16.  One pass.
// ---------------------------------------------------------------------------
__device__ __forceinline__ void splitx_body(const float* src, u16* p1, u16* p2,
                                            u16* pb, int i) {
  const float4 a = *reinterpret_cast<const float4*>(src + (size_t)i * 8);
  const float4 b = *reinterpret_cast<const float4*>(src + (size_t)i * 8 + 4);
  float e[8] = {a.x, a.y, a.z, a.w, b.x, b.y, b.z, b.w};
  short8v v1, v2, vb;
  #pragma unroll
  for (int j = 0; j < 8; ++j) {
    _Float16 h1 = (_Float16)e[j];
    float r = e[j] - (float)h1;
    _Float16 h2 = (_Float16)(r * 256.0f);
    v1[j] = __builtin_bit_cast(short, h1);
    v2[j] = __builtin_bit_cast(short, h2);
    vb[j] = (short)f2bf(e[j]);
  }
  *reinterpret_cast<short8v*>(p1 + (size_t)i * 8) = v1;
  *reinterpret_cast<short8v*>(p2 + (size_t)i * 8) = v2;
  *reinterpret_cast<short8v*>(pb + (size_t)i * 8) = vb;
}

__device__ __forceinline__ void split2h_body(const float* src, u16* p1, u16* p2,
                                             int i) {
  const float4 a = *reinterpret_cast<const float4*>(src + (size_t)i * 8);
  const float4 b = *reinterpret_cast<const float4*>(src + (size_t)i * 8 + 4);
  float e[8] = {a.x, a.y, a.z, a.w, b.x, b.y, b.z, b.w};
  short8v v1, v2;
  #pragma unroll
  for (int j = 0; j < 8; ++j) {
    _Float16 h1 = (_Float16)e[j];
    float r = e[j] - (float)h1;
    _Float16 h2 = (_Float16)(r * 256.0f);
    v1[j] = __builtin_bit_cast(short, h1);
    v2[j] = __builtin_bit_cast(short, h2);
  }
  *reinterpret_cast<short8v*>(p1 + (size_t)i * 8) = v1;
  *reinterpret_cast<short8v*>(p2 + (size_t)i * 8) = v2;
}

__device__ __forceinline__ void conv_body(const float* src, u16* dst, int i) {
  const float4 a = *reinterpret_cast<const float4*>(src + (size_t)i * 8);
  const float4 b = *reinterpret_cast<const float4*>(src + (size_t)i * 8 + 4);
  short8v v;
  v[0] = (short)f2bf(a.x); v[1] = (short)f2bf(a.y);
  v[2] = (short)f2bf(a.z); v[3] = (short)f2bf(a.w);
  v[4] = (short)f2bf(b.x); v[5] = (short)f2bf(b.y);
  v[6] = (short)f2bf(b.z); v[7] = (short)f2bf(b.w);
  *reinterpret_cast<short8v*>(dst + (size_t)i * 8) = v;
}

__global__ __launch_bounds__(256) void prep_all(
    const float* __restrict__ x,  const float* __restrict__ Wq,
    const float* __restrict__ Wk, const float* __restrict__ Wv,
    const float* __restrict__ Wo,
    u16* __restrict__ xh1, u16* __restrict__ xh2, u16* __restrict__ x1b,
    u16* __restrict__ wqh1, u16* __restrict__ wqh2,
    u16* __restrict__ Wkb, u16* __restrict__ Wvb, u16* __restrict__ Wob)
{
  const int NX = MROWS * DM / 8;   // 1048576
  const int NW = DM * DM / 8;      // 131072
  int i = blockIdx.x * 256 + threadIdx.x;
  if (i < NX)  { splitx_body(x, xh1, xh2, x1b, i); return; }
  i -= NX;
  if (i < NW)  { split2h_body(Wq, wqh1, wqh2, i); return; }
  i -= NW;
  if (i < NW)  { conv_body(Wk, Wkb, i); return; }
  i -= NW;
  if (i < NW)  { conv_body(Wv, Wvb, i); return; }
  i -= NW;
  if (i < NW)  { conv_body(Wo, Wob, i); }
}

// ---------------------------------------------------------------------------
// Q-projection body: fp16 2-piece split, 3 products, dual fp32 accumulators
// (validated round 7: selection & absmax identical to bf16-6).  Fused norms.
// smem use: 4 x 4096 u16 = 32KB.
// ---------------------------------------------------------------------------
__device__ __forceinline__ void proj_q_body(
    u16* smem,
    const u16* __restrict__ X1, const u16* __restrict__ X2,
    const u16* __restrict__ W1, const u16* __restrict__ W2,
    const float* __restrict__ bias, float* __restrict__ Y,
    float* __restrict__ norms, int bx, int ny)
{
  u16* As1 = smem;
  u16* As2 = smem + 4096;
  u16* Bs1 = smem + 8192;
  u16* Bs2 = smem + 12288;
  const int tid = threadIdx.x;
  const int m0 = bx * 128, n0 = ny * 128;
  const int wid = tid >> 6, lane = tid & 63;
  const int wr = (wid >> 1) * 64, wc = (wid & 1) * 64;
  const int c = lane & 15, G = lane >> 4;

  int Rr[2], Cr[2];
  #pragma unroll
  for (int rr = 0; rr < 2; ++rr) inv_swz((tid + rr * 256) * 8, Rr[rr], Cr[rr]);

  f32x4 acc0[4][4], acc1[4][4];
  #pragma unroll
  for (int mt = 0; mt < 4; ++mt)
    #pragma unroll
    for (int nt = 0; nt < 4; ++nt) {
      acc0[mt][nt] = (f32x4){0.f, 0.f, 0.f, 0.f};
      acc1[mt][nt] = (f32x4){0.f, 0.f, 0.f, 0.f};
    }

  for (int k0 = 0; k0 < DM; k0 += 32) {
    #pragma unroll
    for (int rr = 0; rr < 2; ++rr) {
      const size_t goA = (size_t)(m0 + Rr[rr]) * DM + k0 + Cr[rr] * 8;
      const size_t goB = (size_t)(n0 + Rr[rr]) * DM + k0 + Cr[rr] * 8;
      const int lb = wid * 512 + rr * 2048;
      gl16(X1 + goA, As1 + lb);
      gl16(X2 + goA, As2 + lb);
      gl16(W1 + goB, Bs1 + lb);
      gl16(W2 + goB, Bs2 + lb);
    }
    __syncthreads();

    half8v bf1[4], bf2[4];
    #pragma unroll
    for (int nt = 0; nt < 4; ++nt) {
      const int n = wc + nt * 16 + c;
      const int eo = (n * 32 + G * 8) ^ ((n & 7) << 3);
      bf1[nt] = *reinterpret_cast<const half8v*>(Bs1 + eo);
      bf2[nt] = *reinterpret_cast<const half8v*>(Bs2 + eo);
    }
    #pragma unroll
    for (int mt = 0; mt < 4; ++mt) {
      const int m = wr + mt * 16 + c;
      const int eo = (m * 32 + G * 8) ^ ((m & 7) << 3);
      half8v a1 = *reinterpret_cast<const half8v*>(As1 + eo);
      half8v a2 = *reinterpret_cast<const half8v*>(As2 + eo);
      #pragma unroll
      for (int nt = 0; nt < 4; ++nt) {
        acc0[mt][nt] = __builtin_amdgcn_mfma_f32_16x16x32_f16(a1, bf1[nt], acc0[mt][nt], 0, 0, 0);
        acc1[mt][nt] = __builtin_amdgcn_mfma_f32_16x16x32_f16(a1, bf2[nt], acc1[mt][nt], 0, 0, 0);
        acc1[mt][nt] = __builtin_amdgcn_mfma_f32_16x16x32_f16(a2, bf1[nt], acc1[mt][nt], 0, 0, 0);
      }
    }
    __syncthreads();
  }

  float bb[4];
  #pragma unroll
  for (int nt = 0; nt < 4; ++nt) bb[nt] = bias[n0 + wc + nt * 16 + c];

  float ns[4][4];
  #pragma unroll
  for (int mt = 0; mt < 4; ++mt)
    #pragma unroll
    for (int r = 0; r < 4; ++r) ns[mt][r] = 0.f;

  constexpr float INV256 = 1.0f / 256.0f;
  #pragma unroll
  for (int mt = 0; mt < 4; ++mt) {
    #pragma unroll
    for (int nt = 0; nt < 4; ++nt) {
      const int n = n0 + wc + nt * 16 + c;
      const int h = n >> 6, d = n & 63;
      #pragma unroll
      for (int r = 0; r < 4; ++r) {
        const int m = m0 + wr + mt * 16 + G * 4 + r;
        const int b = m >> 12, l = m & (LSEQ - 1);
        const float val = acc0[mt][nt][r] + acc1[mt][nt][r] * INV256 + bb[nt];
        Y[((size_t)((b << 4) + h) * LSEQ + l) * HD + d] = val;
        ns[mt][r] = fmaf(val, val, ns[mt][r]);
      }
    }
  }
  #pragma unroll
  for (int mt = 0; mt < 4; ++mt)
    #pragma unroll
    for (int r = 0; r < 4; ++r) {
      float v = ns[mt][r];
      v += __shfl_xor(v, 1); v += __shfl_xor(v, 2);
      v += __shfl_xor(v, 4); v += __shfl_xor(v, 8);
      ns[mt][r] = v;
    }
  if (c == 0) {
    const int h = (n0 + wc) >> 6;
    #pragma unroll
    for (int mt = 0; mt < 4; ++mt)
      #pragma unroll
      for (int r = 0; r < 4; ++r) {
        const int m = m0 + wr + mt * 16 + G * 4 + r;
        const int b = m >> 12, l = m & (LSEQ - 1);
        norms[(((size_t)((b << 4) + h)) << 12) + l] = ns[mt][r];
      }
  }
}

// ---------------------------------------------------------------------------
// K/V projection body (bf16 MFMA).  isV: transposed per-head out via LDS T.
// ---------------------------------------------------------------------------
__device__ __forceinline__ void proj_kv_body(
    u16* smem, const u16* __restrict__ Xb, const u16* __restrict__ Wb,
    const float* __restrict__ bias, u16* __restrict__ Kb, u16* __restrict__ VgT,
    bool isV, int bx, int ny)
{
  u16* As = smem;
  u16* Bs = smem + 4096;
  const int tid = threadIdx.x;
  const int m0 = bx * 128, n0 = ny * 128;
  const int wid = tid >> 6, lane = tid & 63;
  const int wr = (wid >> 1) * 64, wc = (wid & 1) * 64;
  const int c = lane & 15, G = lane >> 4;

  int Rr[2], Cr[2];
  #pragma unroll
  for (int rr = 0; rr < 2; ++rr) inv_swz((tid + rr * 256) * 8, Rr[rr], Cr[rr]);

  f32x4 acc[4][4];
  #pragma unroll
  for (int mt = 0; mt < 4; ++mt)
    #pragma unroll
    for (int nt = 0; nt < 4; ++nt)
      acc[mt][nt] = (f32x4){0.f, 0.f, 0.f, 0.f};

  for (int k0 = 0; k0 < DM; k0 += 32) {
    #pragma unroll
    for (int rr = 0; rr < 2; ++rr) {
      const size_t goA = (size_t)(m0 + Rr[rr]) * DM + k0 + Cr[rr] * 8;
      const size_t goB = (size_t)(n0 + Rr[rr]) * DM + k0 + Cr[rr] * 8;
      const int lb = wid * 512 + rr * 2048;
      gl16(Xb + goA, As + lb);
      gl16(Wb + goB, Bs + lb);
    }
    __syncthreads();

    short8v af[4], bf[4];
    #pragma unroll
    for (int mt = 0; mt < 4; ++mt) {
      const int m = wr + mt * 16 + c;
      af[mt] = *reinterpret_cast<const short8v*>(As + ((m * 32 + G * 8) ^ ((m & 7) << 3)));
      const int n = wc + mt * 16 + c;
      bf[mt] = *reinterpret_cast<const short8v*>(Bs + ((n * 32 + G * 8) ^ ((n & 7) << 3)));
    }
    #pragma unroll
    for (int mt = 0; mt < 4; ++mt)
      #pragma unroll
      for (int nt = 0; nt < 4; ++nt)
        acc[mt][nt] = __builtin_amdgcn_mfma_f32_16x16x32_bf16(af[mt], bf[nt], acc[mt][nt], 0, 0, 0);
    __syncthreads();
  }

  float bb[4];
  #pragma unroll
  for (int nt = 0; nt < 4; ++nt) bb[nt] = bias[n0 + wc + nt * 16 + c];

  if (isV) {
    #pragma unroll
    for (int mt = 0; mt < 4; ++mt) {
      #pragma unroll
      for (int nt = 0; nt < 4; ++nt) {
        const int n = wc + nt * 16 + c;
        const int mloc = wr + mt * 16 + G * 4;
        short4v pv;
        #pragma unroll
        for (int r = 0; r < 4; ++r) pv[r] = (short)f2bf(acc[mt][nt][r] + bb[nt]);
        *reinterpret_cast<short4v*>(smem + n * 136 + mloc) = pv;
      }
    }
    __syncthreads();
    const int bb2 = m0 >> 12;
    const int ml0 = m0 & (LSEQ - 1);
    #pragma unroll
    for (int uu = 0; uu < 8; ++uu) {
      const int u = uu * 256 + tid;
      const int n = u >> 4, kg = u & 15;
      short8v vvv = *reinterpret_cast<const short8v*>(smem + n * 136 + kg * 8);
      const int h = (n0 + n) >> 6, d = (n0 + n) & 63;
      *reinterpret_cast<short8v*>(
          VgT + ((size_t)((bb2 << 4) + h) * HD + d) * LSEQ + ml0 + kg * 8) = vvv;
    }
  } else {
    #pragma unroll
    for (int mt = 0; mt < 4; ++mt) {
      #pragma unroll
      for (int nt = 0; nt < 4; ++nt) {
        const int n = n0 + wc + nt * 16 + c;
        const int h = n >> 6, d = n & 63;
        #pragma unroll
        for (int r = 0; r < 4; ++r) {
          const int m = m0 + wr + mt * 16 + G * 4 + r;
          const int b = m >> 12, l = m & (LSEQ - 1);
          Kb[((size_t)((b << 4) + h) * LSEQ + l) * HD + d] = f2bf(acc[mt][nt][r] + bb[nt]);
        }
      }
    }
  }
}

// ---------------------------------------------------------------------------
// Fused projection: by(+y_off) < 8 -> Q (fp16 2pc); 8..15 -> V; >=16 -> K.
// ---------------------------------------------------------------------------
__global__ __launch_bounds__(256) void gemm_proj(
    const u16* __restrict__ X1, const u16* __restrict__ X2, const u16* __restrict__ Xb,
    const u16* __restrict__ W1, const u16* __restrict__ W2,
    const u16* __restrict__ Wkb, const u16* __restrict__ Wvb,
    const float* __restrict__ bq, const float* __restrict__ bk, const float* __restrict__ bv,
    float* __restrict__ Qb, float* __restrict__ norms,
    u16* __restrict__ Kb, u16* __restrict__ VgT, int y_off)
{
  __shared__ __align__(16) u16 smem[17408];   // 34816 B union
  const int by = blockIdx.y + y_off;
  const int bx = blockIdx.x;
  if (by < 8) {
    proj_q_body(smem, X1, X2, W1, W2, bq, Qb, norms, bx, by);
  } else if (by < 16) {
    proj_kv_body(smem, Xb, Wvb, bv, Kb, VgT, true, bx, by - 8);
  } else {
    proj_kv_body(smem, Xb, Wkb, bk, Kb, VgT, false, bx, by - 16);
  }
}

// ---------------------------------------------------------------------------
// Output GEMM: out = O1b(bf16) @ Wob^T + bo, fp32 row-major out.
// ---------------------------------------------------------------------------
__global__ __launch_bounds__(256) void gemm_out(
    const u16* __restrict__ Xb, const u16* __restrict__ Wb,
    const float* __restrict__ bias, float* __restrict__ Y)
{
  __shared__ u16 As[128 * 32];
  __shared__ u16 Bs[128 * 32];
  const int tid = threadIdx.x;
  const int m0 = blockIdx.x * 128, n0 = blockIdx.y * 128;
  const int wid = tid >> 6, lane = tid & 63;
  const int wr = (wid >> 1) * 64, wc = (wid & 1) * 64;
  const int c = lane & 15, G = lane >> 4;

  int Rr[2], Cr[2];
  #pragma unroll
  for (int rr = 0; rr < 2; ++rr) inv_swz((tid + rr * 256) * 8, Rr[rr], Cr[rr]);

  f32x4 acc[4][4];
  #pragma unroll
  for (int mt = 0; mt < 4; ++mt)
    #pragma unroll
    for (int nt = 0; nt < 4; ++nt)
      acc[mt][nt] = (f32x4){0.f, 0.f, 0.f, 0.f};

  for (int k0 = 0; k0 < DM; k0 += 32) {
    #pragma unroll
    for (int rr = 0; rr < 2; ++rr) {
      const size_t goA = (size_t)(m0 + Rr[rr]) * DM + k0 + Cr[rr] * 8;
      const size_t goB = (size_t)(n0 + Rr[rr]) * DM + k0 + Cr[rr] * 8;
      const int lb = wid * 512 + rr * 2048;
      gl16(Xb + goA, As + lb);
      gl16(Wb + goB, Bs + lb);
    }
    __syncthreads();

    short8v af[4], bf[4];
    #pragma unroll
    for (int mt = 0; mt < 4; ++mt) {
      const int m = wr + mt * 16 + c;
      af[mt] = *reinterpret_cast<const short8v*>(As + ((m * 32 + G * 8) ^ ((m & 7) << 3)));
      const int n = wc + mt * 16 + c;
      bf[mt] = *reinterpret_cast<const short8v*>(Bs + ((n * 32 + G * 8) ^ ((n & 7) << 3)));
    }
    #pragma unroll
    for (int mt = 0; mt < 4; ++mt)
      #pragma unroll
      for (int nt = 0; nt < 4; ++nt)
        acc[mt][nt] = __builtin_amdgcn_mfma_f32_16x16x32_bf16(af[mt], bf[nt], acc[mt][nt], 0, 0, 0);
    __syncthreads();
  }

  float bb[4];
  #pragma unroll
  for (int nt = 0; nt < 4; ++nt) bb[nt] = bias[n0 + wc + nt * 16 + c];

  #pragma unroll
  for (int mt = 0; mt < 4; ++mt) {
    #pragma unroll
    for (int nt = 0; nt < 4; ++nt) {
      const int n = n0 + wc + nt * 16 + c;
      #pragma unroll
      for (int r = 0; r < 4; ++r) {
        const int m = m0 + wr + mt * 16 + G * 4 + r;
        Y[(size_t)m * DM + n] = acc[mt][nt][r] + bb[nt];
      }
    }
  }
}

// ---------------------------------------------------------------------------
// Per-bh top-TOPU selection (set only) -- byte-radix select + stable compact.
// ---------------------------------------------------------------------------
__global__ __launch_bounds__(1024) void select_topk(
    const float* __restrict__ norms, int* __restrict__ top_idx)
{
  __shared__ unsigned int keys[LSEQ];
  __shared__ unsigned int hist[256];
  __shared__ unsigned int wsums[16];
  __shared__ unsigned int sh_b, sh_above;

  const int tid = threadIdx.x;
  const int bh = blockIdx.x;

  for (int l = tid; l < LSEQ; l += 1024)
    keys[l] = __float_as_uint(norms[bh * LSEQ + l]);
  __syncthreads();

  unsigned int prefix = 0, rem = TOPU, total_gt = 0;
  for (int shift = 24; shift >= 0; shift -= 8) {
    if (tid < 256) hist[tid] = 0;
    __syncthreads();
    for (int l = tid; l < LSEQ; l += 1024) {
      const unsigned int k = keys[l];
      const bool in = (shift == 24) || ((k >> (shift + 8)) == prefix);
      if (in) atomicAdd(&hist[(k >> shift) & 255], 1);
    }
    __syncthreads();
    if (tid == 0) {
      unsigned int cum = 0; int b = 255;
      for (; b > 0; --b) {
        const unsigned int h = hist[b];
        if (cum + h >= rem) break;
        cum += h;
      }
      sh_b = (unsigned int)b; sh_above = cum;
    }
    __syncthreads();
    prefix = (prefix << 8) | sh_b;
    total_gt += sh_above;
    rem -= sh_above;
    __syncthreads();
  }
  const unsigned int T = prefix;

  const int lane = tid & 63, wv = tid >> 6;
  const int l0 = tid * 4;

  {
    unsigned int flags = 0; int cnt = 0;
    #pragma unroll
    for (int j = 0; j < 4; ++j)
      if (keys[l0 + j] > T) { flags |= 1u << j; ++cnt; }
    int incl = cnt;
    #pragma unroll
    for (int off = 1; off < 64; off <<= 1) {
      int nv = __shfl_up(incl, off);
      if (lane >= off) incl += nv;
    }
    if (lane == 63) wsums[wv] = (unsigned int)incl;
    __syncthreads();
    if (tid == 0) {
      unsigned int run = 0;
      for (int w = 0; w < 16; ++w) { unsigned int t = wsums[w]; wsums[w] = run; run += t; }
    }
    __syncthreads();
    unsigned int pos = wsums[wv] + (unsigned int)(incl - cnt);
    #pragma unroll
    for (int j = 0; j < 4; ++j)
      if (flags & (1u << j)) top_idx[bh * TOPU + (pos++)] = l0 + j;
  }
  __syncthreads();

  {
    unsigned int flags = 0; int cnt = 0;
    #pragma unroll
    for (int j = 0; j < 4; ++j)
      if (keys[l0 + j] == T) { flags |= 1u << j; ++cnt; }
    int incl = cnt;
    #pragma unroll
    for (int off = 1; off < 64; off <<= 1) {
      int nv = __shfl_up(incl, off);
      if (lane >= off) incl += nv;
    }
    if (lane == 63) wsums[wv] = (unsigned int)incl;
    __syncthreads();
    if (tid == 0) {
      unsigned int run = 0;
      for (int w = 0; w < 16; ++w) { unsigned int t = wsums[w]; wsums[w] = run; run += t; }
    }
    __syncthreads();
    unsigned int r0 = wsums[wv] + (unsigned int)(incl - cnt);
    #pragma unroll
    for (int j = 0; j < 4; ++j)
      if (flags & (1u << j)) {
        if (r0 < rem) top_idx[bh * TOPU + total_gt + r0] = l0 + j;
        ++r0;
      }
  }
}

// ---------------------------------------------------------------------------
// MFMA flash attention, split-K x4, bf16 partial O + fp32 (m,lsum).
// Grid 1664 = 8 xcd * 208; each xcd owns 4 bh.
// ---------------------------------------------------------------------------
__global__ __launch_bounds__(256) void attn_mfma(
    const float* __restrict__ Qf, const u16* __restrict__ Kg,
    const u16* __restrict__ VgT, const int* __restrict__ tix,
    u16* __restrict__ OpartB, float* __restrict__ MLpart)
{
  __shared__ u16 Kc[128 * 64];
  __shared__ u16 Vt[64 * 128];
  __shared__ u16 Pt[4][16 * 136];

  const int tid = threadIdx.x;
  const int wid = tid >> 6, lane = tid & 63;
  const int c = lane & 15, G = lane >> 4;

  const int l = blockIdx.x;
  const int grp = l >> 3;                  // 0..207
  const int bh = (grp / 52) * 8 + (l & 7);
  const int rem = grp % 52;
  const int qb = rem >> 2, ks = rem & 3;

  const size_t bhL = (size_t)bh * LSEQ;
  const int rglob = qb * 64 + wid * 16 + c;
  const int rowidx = (rglob < TOPU) ? tix[bh * TOPU + rglob] : -1;

  short8v qf[2];
  #pragma unroll
  for (int kf = 0; kf < 2; ++kf) {
    if (rowidx >= 0) {
      const float* qp = Qf + (bhL + rowidx) * HD + kf * 32 + G * 8;
      const float4 x0 = *reinterpret_cast<const float4*>(qp);
      const float4 x1 = *reinterpret_cast<const float4*>(qp + 4);
      short8v v;
      v[0] = (short)f2bf(x0.x * 0.125f); v[1] = (short)f2bf(x0.y * 0.125f);
      v[2] = (short)f2bf(x0.z * 0.125f); v[3] = (short)f2bf(x0.w * 0.125f);
      v[4] = (short)f2bf(x1.x * 0.125f); v[5] = (short)f2bf(x1.y * 0.125f);
      v[6] = (short)f2bf(x1.z * 0.125f); v[7] = (short)f2bf(x1.w * 0.125f);
      qf[kf] = v;
    } else {
      short8v v;
      #pragma unroll
      for (int j = 0; j < 8; ++j) v[j] = 0;
      qf[kf] = v;
    }
  }

  float m = -1e30f, lsum = 0.f;
  f32x4 oacc[4];
  #pragma unroll
  for (int dt = 0; dt < 4; ++dt) oacc[dt] = (f32x4){0.f, 0.f, 0.f, 0.f};

  const int ko0 = ks * (LSEQ / NSEG);
  const int wbase = (tid & ~63) * 8;
  for (int t = 0; t < LSEQ / NSEG / 128; ++t) {
    const int ko = ko0 + t * 128;
    #pragma unroll
    for (int uu = 0; uu < 4; ++uu) {
      const int S = (uu * 256 + tid) * 8;
      const int key = S >> 6, dgk = ((S >> 3) & 7) ^ (key & 7);
      gl16(Kg + (bhL + ko + key) * HD + dgk * 8, Kc + uu * 2048 + wbase);
      const int d = S >> 7, kgv = ((S >> 3) & 15) ^ (d & 7);
      gl16(VgT + ((size_t)bh * HD + d) * LSEQ + ko + kgv * 8, Vt + uu * 2048 + wbase);
    }
    __syncthreads();

    f32x4 sacc[8];
    __builtin_amdgcn_s_setprio(1);
    #pragma unroll
    for (int kt = 0; kt < 8; ++kt) {
      const int key = kt * 16 + c;
      short8v kb0 = *reinterpret_cast<const short8v*>(
          Kc + key * 64 + (((0 + G) ^ (key & 7)) << 3));
      short8v kb1 = *reinterpret_cast<const short8v*>(
          Kc + key * 64 + (((4 + G) ^ (key & 7)) << 3));
      f32x4 s = (f32x4){0.f, 0.f, 0.f, 0.f};
      s = __builtin_amdgcn_mfma_f32_16x16x32_bf16(kb0, qf[0], s, 0, 0, 0);
      s = __builtin_amdgcn_mfma_f32_16x16x32_bf16(kb1, qf[1], s, 0, 0, 0);
      sacc[kt] = s;
    }
    __builtin_amdgcn_s_setprio(0);

    float smax = -1e30f;
    #pragma unroll
    for (int kt = 0; kt < 8; ++kt) {
      float a0 = fmaxf(sacc[kt][0], sacc[kt][1]);
      float a1 = fmaxf(sacc[kt][2], sacc[kt][3]);
      smax = fmaxf(smax, fmaxf(a0, a1));
    }
    smax = fmaxf(smax, __shfl_xor(smax, 16));
    smax = fmaxf(smax, __shfl_xor(smax, 32));
    const float mnew = fmaxf(m, smax);
    const float corr = __expf(m - mnew);
    float ssum = 0.f;
    #pragma unroll
    for (int kt = 0; kt < 8; ++kt) {
      float p0 = __expf(sacc[kt][0] - mnew);
      float p1 = __expf(sacc[kt][1] - mnew);
      float p2 = __expf(sacc[kt][2] - mnew);
      float p3 = __expf(sacc[kt][3] - mnew);
      ssum += (p0 + p1) + (p2 + p3);
      short4v pv;
      pv[0] = (short)f2bf(p0); pv[1] = (short)f2bf(p1);
      pv[2] = (short)f2bf(p2); pv[3] = (short)f2bf(p3);
      *reinterpret_cast<short4v*>(&Pt[wid][c * 136 + kt * 16 + G * 4]) = pv;
    }
    ssum += __shfl_xor(ssum, 16);
    ssum += __shfl_xor(ssum, 32);
    lsum = lsum * corr + ssum;
    m = mnew;
    #pragma unroll
    for (int dt = 0; dt < 4; ++dt) oacc[dt] *= corr;

    __builtin_amdgcn_s_setprio(1);
    #pragma unroll
    for (int kf = 0; kf < 4; ++kf) {
      short8v pf = *reinterpret_cast<const short8v*>(
          &Pt[wid][c * 136 + kf * 32 + G * 8]);
      #pragma unroll
      for (int dt = 0; dt < 4; ++dt) {
        const int d = dt * 16 + c;
        short8v vf = *reinterpret_cast<const short8v*>(
            Vt + d * 128 + (((kf * 4 + G) ^ (d & 7)) << 3));
        oacc[dt] = __builtin_amdgcn_mfma_f32_16x16x32_bf16(vf, pf, oacc[dt], 0, 0, 0);
      }
    }
    __builtin_amdgcn_s_setprio(0);
    __syncthreads();
  }

  const int q = wid * 16 + c;
  const size_t pb = ((size_t)((bh * 13 + qb) * NSEG + ks)) * 64 + q;
  u16* op = OpartB + pb * 64;
  #pragma unroll
  for (int dt = 0; dt < 4; ++dt) {
    short4v o;
    o[0] = (short)f2bf(oacc[dt][0]); o[1] = (short)f2bf(oacc[dt][1]);
    o[2] = (short)f2bf(oacc[dt][2]); o[3] = (short)f2bf(oacc[dt][3]);
    *reinterpret_cast<short4v*>(op + dt * 16 + G * 4) = o;
  }
  if (G == 0) {
    MLpart[pb * 2]     = m;
    MLpart[pb * 2 + 1] = lsum;
  }
}

// ---------------------------------------------------------------------------
// 4-way split-K combine: O = sum_i Oi*ci / sum_i li*ci, scatter bf16 to O1b.
// ---------------------------------------------------------------------------
__global__ __launch_bounds__(256) void attn_combine(
    const u16* __restrict__ OpartB, const float* __restrict__ MLpart,
    const int* __restrict__ tix, u16* __restrict__ O1b)
{
  const int bq = blockIdx.x;
  const int bh = bq / 13, qb = bq % 13;
  const int tid = threadIdx.x;
  const int q = tid >> 2, dq = (tid & 3) * 16;
  const int rglob = qb * 64 + q;
  if (rglob >= TOPU) return;
  const int rowidx = tix[bh * TOPU + rglob];

  size_t p[NSEG];
  float mi[NSEG], li[NSEG];
  #pragma unroll
  for (int i = 0; i < NSEG; ++i) {
    p[i] = ((size_t)bq * NSEG + i) * 64 + q;
    mi[i] = MLpart[p[i] * 2];
    li[i] = MLpart[p[i] * 2 + 1];
  }
  float mx = fmaxf(fmaxf(mi[0], mi[1]), fmaxf(mi[2], mi[3]));
  float ci[NSEG], lsum = 0.f;
  #pragma unroll
  for (int i = 0; i < NSEG; ++i) { ci[i] = __expf(mi[i] - mx); lsum += li[i] * ci[i]; }
  const float linv = 1.0f / lsum;

  float acc[16];
  #pragma unroll
  for (int j = 0; j < 16; ++j) acc[j] = 0.f;
  #pragma unroll
  for (int i = 0; i < NSEG; ++i) {
    const u16* src = OpartB + p[i] * 64 + dq;
    #pragma unroll
    for (int j = 0; j < 16; ++j) acc[j] += bf2f(src[j]) * ci[i];
  }

  const int b = bh >> 4, h = bh & 15;
  u16* dst = O1b + (size_t)(b * LSEQ + rowidx) * DM + h * HD + dq;
  #pragma unroll
  for (int j0 = 0; j0 < 16; j0 += 4) {
    short4v o;
    #pragma unroll
    for (int j = 0; j < 4; ++j) o[j] = (short)f2bf(acc[j0 + j] * linv);
    *reinterpret_cast<short4v*>(dst + j0) = o;
  }
}

// ---------------------------------------------------------------------------
extern "C" void kernel_launch(void* const* d_in, const int* in_sizes, int n_in,
                              void* d_out, int out_size, void* d_ws, size_t ws_size,
                              hipStream_t stream) {
  const float* x  = (const float*)d_in[0];
  const float* Wq = (const float*)d_in[1];
  const float* bq = (const float*)d_in[2];
  const float* Wk = (const float*)d_in[3];
  const float* bk = (const float*)d_in[4];
  const float* Wv = (const float*)d_in[5];
  const float* bv = (const float*)d_in[6];
  const float* Wo = (const float*)d_in[7];
  const float* bo = (const float*)d_in[8];
  float* out = (float*)d_out;

  char* w = (char*)d_ws;
  float* Qb = (float*)w;  w += (size_t)BHT * LSEQ * HD * 4;    // 32 MB
  u16* xh1  = (u16*)w;    w += (size_t)MROWS * DM * 2;         // 16 MB -> O1b
  u16* xh2  = (u16*)w;    w += (size_t)MROWS * DM * 2;         // 16 MB -> Opart (fused) / Kb (fallback)
  u16* x1b  = (u16*)w;    w += (size_t)MROWS * DM * 2;         // 16 MB -> Opart (fallback)
  u16* VgT  = (u16*)w;    w += (size_t)BHT * HD * LSEQ * 2;    // 16 MB
  u16* Wkb  = (u16*)w;    w += (size_t)DM * DM * 2;            // 2 MB
  u16* Wvb  = (u16*)w;    w += (size_t)DM * DM * 2;
  u16* Wob  = (u16*)w;    w += (size_t)DM * DM * 2;
  u16* wqh1 = (u16*)w;    w += (size_t)DM * DM * 2;
  u16* wqh2 = (u16*)w;    w += (size_t)DM * DM * 2;            // -> tix
  float* norms = (float*)w; w += (size_t)BHT * LSEQ * 4;       // 512 KB
  u16* Kb_ext = (u16*)w;  w += (size_t)BHT * LSEQ * HD * 2;    // 16 MB (if room)

  const bool fusedK = ws_size >= (size_t)(w - (char*)d_ws);
  u16* Kb       = fusedK ? Kb_ext : xh2;      // fallback: K written after Q/V launch
  u16* OpartB   = fusedK ? xh2 : x1b;         // dead input regions reused
  const int NPB = BHT * 13 * NSEG * 64;       // partial rows = 106496
  float* MLpart = (float*)(OpartB + (size_t)NPB * 64);
  u16*   O1b    = xh1;
  int*   tix    = (int*)wqh2;

  prep_all<<<6144, 256, 0, stream>>>(x, Wq, Wk, Wv, Wo,
                                     xh1, xh2, x1b, wqh1, wqh2, Wkb, Wvb, Wob);

  if (fusedK) {
    gemm_proj<<<dim3(64, 24), 256, 0, stream>>>(
        xh1, xh2, x1b, wqh1, wqh2, Wkb, Wvb, bq, bk, bv, Qb, norms, Kb, VgT, 0);
  } else {
    gemm_proj<<<dim3(64, 16), 256, 0, stream>>>(
        xh1, xh2, x1b, wqh1, wqh2, Wkb, Wvb, bq, bk, bv, Qb, norms, Kb, VgT, 0);
    gemm_proj<<<dim3(64, 8), 256, 0, stream>>>(
        xh1, xh2, x1b, wqh1, wqh2, Wkb, Wvb, bq, bk, bv, Qb, norms, Kb, VgT, 16);
  }

  select_topk<<<BHT, 1024, 0, stream>>>(norms, tix);

  hipMemsetAsync(O1b, 0, (size_t)MROWS * DM * 2, stream);

  attn_mfma<<<BHT * 13 * NSEG, 256, 0, stream>>>(Qb, Kb, VgT, tix, OpartB, MLpart);
  attn_combine<<<BHT * 13, 256, 0, stream>>>(OpartB, MLpart, tix, O1b);

  gemm_out<<<dim3(MROWS / 128, DM / 128), 256, 0, stream>>>(O1b, Wob, bo, out);
}

// Round 10
// 287.257 us; speedup vs baseline: 1.1335x; 1.1335x over previous
//
#include <hip/hip_runtime.h>
#include <cstddef>
#include <cstdint>

constexpr int LSEQ = 4096;
constexpr int DM   = 1024;
constexpr int HD   = 64;
constexpr int BHT  = 32;     // B*H
constexpr int TOPU = 819;
constexpr int MROWS = 8192;  // B*L
constexpr int NSEG = 4;      // attention split-K segments

typedef unsigned short u16;
typedef __attribute__((ext_vector_type(8))) short short8v;  // 8 bf16 (4 VGPR)
typedef __attribute__((ext_vector_type(4))) short short4v;  // 4 bf16 (8B)
typedef __attribute__((ext_vector_type(4))) float f32x4;

__device__ __forceinline__ u16 f2bf(float f) {
  uint32_t u = __float_as_uint(f);
  u += 0x7fffu + ((u >> 16) & 1u);   // RNE
  return (u16)(u >> 16);
}
__device__ __forceinline__ float bf2f(u16 h) {
  return __uint_as_float(((uint32_t)h) << 16);
}

// async 16B global -> LDS (DMA).  LDS dest wave-uniform base; HW adds lane*16.
__device__ __forceinline__ void gl16(const void* g, void* l) {
  __builtin_amdgcn_global_load_lds(
      (const __attribute__((address_space(1))) void*)g,
      (__attribute__((address_space(3))) void*)l, 16, 0, 0);
}

// Inverse of the LDS swizzle e = (R*32 + C*8) ^ ((R&7)<<3) for linear slot S.
__device__ __forceinline__ void inv_swz(int S, int& R, int& C) {
  const int R0 = ((S >> 5) ^ (S >> 7)) & 1;
  const int R1 = (S >> 6) & 1;
  R = ((S >> 6) << 1) | R0;
  C = (((S >> 3) & 1) ^ R0) | ((((S >> 4) & 1) ^ R1) << 1);
}

// ---------------------------------------------------------------------------
// Fused prep: split3(x), split3(Wq), conv(Wk), conv(Wv), conv(Wo) in one pass.
// ---------------------------------------------------------------------------
__device__ __forceinline__ void split3_body(const float* src, u16* p1, u16* p2,
                                            u16* p3, int i) {
  const float4 a = *reinterpret_cast<const float4*>(src + (size_t)i * 8);
  const float4 b = *reinterpret_cast<const float4*>(src + (size_t)i * 8 + 4);
  float e[8] = {a.x, a.y, a.z, a.w, b.x, b.y, b.z, b.w};
  short8v v1, v2, v3;
  #pragma unroll
  for (int j = 0; j < 8; ++j) {
    u16 h1 = f2bf(e[j]);        float r1 = e[j] - bf2f(h1);
    u16 h2 = f2bf(r1);          float r2 = r1 - bf2f(h2);
    u16 h3 = f2bf(r2);
    v1[j] = (short)h1; v2[j] = (short)h2; v3[j] = (short)h3;
  }
  *reinterpret_cast<short8v*>(p1 + (size_t)i * 8) = v1;
  *reinterpret_cast<short8v*>(p2 + (size_t)i * 8) = v2;
  *reinterpret_cast<short8v*>(p3 + (size_t)i * 8) = v3;
}

__device__ __forceinline__ void conv_body(const float* src, u16* dst, int i) {
  const float4 a = *reinterpret_cast<const float4*>(src + (size_t)i * 8);
  const float4 b = *reinterpret_cast<const float4*>(src + (size_t)i * 8 + 4);
  short8v v;
  v[0] = (short)f2bf(a.x); v[1] = (short)f2bf(a.y);
  v[2] = (short)f2bf(a.z); v[3] = (short)f2bf(a.w);
  v[4] = (short)f2bf(b.x); v[5] = (short)f2bf(b.y);
  v[6] = (short)f2bf(b.z); v[7] = (short)f2bf(b.w);
  *reinterpret_cast<short8v*>(dst + (size_t)i * 8) = v;
}

__global__ __launch_bounds__(256) void prep_all(
    const float* __restrict__ x,  const float* __restrict__ Wq,
    const float* __restrict__ Wk, const float* __restrict__ Wv,
    const float* __restrict__ Wo,
    u16* __restrict__ x1, u16* __restrict__ x2, u16* __restrict__ x3,
    u16* __restrict__ wq1, u16* __restrict__ wq2, u16* __restrict__ wq3,
    u16* __restrict__ Wkb, u16* __restrict__ Wvb, u16* __restrict__ Wob)
{
  const int NX = MROWS * DM / 8;   // 1048576
  const int NW = DM * DM / 8;      // 131072
  int i = blockIdx.x * 256 + threadIdx.x;
  if (i < NX)  { split3_body(x,  x1,  x2,  x3,  i); return; }
  i -= NX;
  if (i < NW)  { split3_body(Wq, wq1, wq2, wq3, i); return; }
  i -= NW;
  if (i < NW)  { conv_body(Wk, Wkb, i); return; }
  i -= NW;
  if (i < NW)  { conv_body(Wv, Wvb, i); return; }
  i -= NW;
  if (i < NW)  { conv_body(Wo, Wob, i); }
}

// ---------------------------------------------------------------------------
// Q-projection body (bf16 3-piece split, 6 products, fp32-accurate) + fused
// per-row norms.  smem: 6 x 4096 u16 (48KB).  Single acc array => VGPR ~116.
// ---------------------------------------------------------------------------
__device__ __forceinline__ void proj_q_body(
    u16* smem,
    const u16* __restrict__ X1, const u16* __restrict__ X2, const u16* __restrict__ X3,
    const u16* __restrict__ W1, const u16* __restrict__ W2, const u16* __restrict__ W3,
    const float* __restrict__ bias, float* __restrict__ Y,
    float* __restrict__ norms, int bx, int ny)
{
  u16* As[3] = {smem, smem + 4096, smem + 8192};
  u16* Bs[3] = {smem + 12288, smem + 16384, smem + 20480};
  const int tid = threadIdx.x;
  const int m0 = bx * 128, n0 = ny * 128;
  const int wid = tid >> 6, lane = tid & 63;
  const int wr = (wid >> 1) * 64, wc = (wid & 1) * 64;
  const int c = lane & 15, G = lane >> 4;

  int Rr[2], Cr[2];
  #pragma unroll
  for (int rr = 0; rr < 2; ++rr) inv_swz((tid + rr * 256) * 8, Rr[rr], Cr[rr]);

  f32x4 acc[4][4];
  #pragma unroll
  for (int mt = 0; mt < 4; ++mt)
    #pragma unroll
    for (int nt = 0; nt < 4; ++nt)
      acc[mt][nt] = (f32x4){0.f, 0.f, 0.f, 0.f};

  for (int k0 = 0; k0 < DM; k0 += 32) {
    #pragma unroll
    for (int rr = 0; rr < 2; ++rr) {
      const size_t goA = (size_t)(m0 + Rr[rr]) * DM + k0 + Cr[rr] * 8;
      const size_t goB = (size_t)(n0 + Rr[rr]) * DM + k0 + Cr[rr] * 8;
      const int lb = wid * 512 + rr * 2048;
      gl16(X1 + goA, As[0] + lb);
      gl16(X2 + goA, As[1] + lb);
      gl16(X3 + goA, As[2] + lb);
      gl16(W1 + goB, Bs[0] + lb);
      gl16(W2 + goB, Bs[1] + lb);
      gl16(W3 + goB, Bs[2] + lb);
    }
    __syncthreads();

    short8v bf[3][4];
    #pragma unroll
    for (int nt = 0; nt < 4; ++nt) {
      const int n = wc + nt * 16 + c;
      const int eo = (n * 32 + G * 8) ^ ((n & 7) << 3);
      bf[0][nt] = *reinterpret_cast<const short8v*>(Bs[0] + eo);
      bf[1][nt] = *reinterpret_cast<const short8v*>(Bs[1] + eo);
      bf[2][nt] = *reinterpret_cast<const short8v*>(Bs[2] + eo);
    }
    #pragma unroll
    for (int mt = 0; mt < 4; ++mt) {
      const int m = wr + mt * 16 + c;
      const int eo = (m * 32 + G * 8) ^ ((m & 7) << 3);
      short8v a1 = *reinterpret_cast<const short8v*>(As[0] + eo);
      short8v a2 = *reinterpret_cast<const short8v*>(As[1] + eo);
      short8v a3 = *reinterpret_cast<const short8v*>(As[2] + eo);
      #pragma unroll
      for (int nt = 0; nt < 4; ++nt) {
        acc[mt][nt] = __builtin_amdgcn_mfma_f32_16x16x32_bf16(a1, bf[0][nt], acc[mt][nt], 0, 0, 0);
        acc[mt][nt] = __builtin_amdgcn_mfma_f32_16x16x32_bf16(a1, bf[1][nt], acc[mt][nt], 0, 0, 0);
        acc[mt][nt] = __builtin_amdgcn_mfma_f32_16x16x32_bf16(a2, bf[0][nt], acc[mt][nt], 0, 0, 0);
        acc[mt][nt] = __builtin_amdgcn_mfma_f32_16x16x32_bf16(a2, bf[1][nt], acc[mt][nt], 0, 0, 0);
        acc[mt][nt] = __builtin_amdgcn_mfma_f32_16x16x32_bf16(a1, bf[2][nt], acc[mt][nt], 0, 0, 0);
        acc[mt][nt] = __builtin_amdgcn_mfma_f32_16x16x32_bf16(a3, bf[0][nt], acc[mt][nt], 0, 0, 0);
      }
    }
    __syncthreads();
  }

  float bb[4];
  #pragma unroll
  for (int nt = 0; nt < 4; ++nt) bb[nt] = bias[n0 + wc + nt * 16 + c];

  float ns[4][4];
  #pragma unroll
  for (int mt = 0; mt < 4; ++mt)
    #pragma unroll
    for (int r = 0; r < 4; ++r) ns[mt][r] = 0.f;

  #pragma unroll
  for (int mt = 0; mt < 4; ++mt) {
    #pragma unroll
    for (int nt = 0; nt < 4; ++nt) {
      const int n = n0 + wc + nt * 16 + c;
      const int h = n >> 6, d = n & 63;
      #pragma unroll
      for (int r = 0; r < 4; ++r) {
        const int m = m0 + wr + mt * 16 + G * 4 + r;
        const int b = m >> 12, l = m & (LSEQ - 1);
        const float val = acc[mt][nt][r] + bb[nt];
        Y[((size_t)((b << 4) + h) * LSEQ + l) * HD + d] = val;
        ns[mt][r] = fmaf(val, val, ns[mt][r]);
      }
    }
  }
  #pragma unroll
  for (int mt = 0; mt < 4; ++mt)
    #pragma unroll
    for (int r = 0; r < 4; ++r) {
      float v = ns[mt][r];
      v += __shfl_xor(v, 1); v += __shfl_xor(v, 2);
      v += __shfl_xor(v, 4); v += __shfl_xor(v, 8);
      ns[mt][r] = v;
    }
  if (c == 0) {
    const int h = (n0 + wc) >> 6;
    #pragma unroll
    for (int mt = 0; mt < 4; ++mt)
      #pragma unroll
      for (int r = 0; r < 4; ++r) {
        const int m = m0 + wr + mt * 16 + G * 4 + r;
        const int b = m >> 12, l = m & (LSEQ - 1);
        norms[(((size_t)((b << 4) + h)) << 12) + l] = ns[mt][r];
      }
  }
}

// ---------------------------------------------------------------------------
// K/V projection body (bf16 MFMA).  isV: transposed per-head out via LDS T.
// ---------------------------------------------------------------------------
__device__ __forceinline__ void proj_kv_body(
    u16* smem, const u16* __restrict__ Xb, const u16* __restrict__ Wb,
    const float* __restrict__ bias, u16* __restrict__ Kb, u16* __restrict__ VgT,
    bool isV, int bx, int ny)
{
  u16* As = smem;
  u16* Bs = smem + 4096;
  const int tid = threadIdx.x;
  const int m0 = bx * 128, n0 = ny * 128;
  const int wid = tid >> 6, lane = tid & 63;
  const int wr = (wid >> 1) * 64, wc = (wid & 1) * 64;
  const int c = lane & 15, G = lane >> 4;

  int Rr[2], Cr[2];
  #pragma unroll
  for (int rr = 0; rr < 2; ++rr) inv_swz((tid + rr * 256) * 8, Rr[rr], Cr[rr]);

  f32x4 acc[4][4];
  #pragma unroll
  for (int mt = 0; mt < 4; ++mt)
    #pragma unroll
    for (int nt = 0; nt < 4; ++nt)
      acc[mt][nt] = (f32x4){0.f, 0.f, 0.f, 0.f};

  for (int k0 = 0; k0 < DM; k0 += 32) {
    #pragma unroll
    for (int rr = 0; rr < 2; ++rr) {
      const size_t goA = (size_t)(m0 + Rr[rr]) * DM + k0 + Cr[rr] * 8;
      const size_t goB = (size_t)(n0 + Rr[rr]) * DM + k0 + Cr[rr] * 8;
      const int lb = wid * 512 + rr * 2048;
      gl16(Xb + goA, As + lb);
      gl16(Wb + goB, Bs + lb);
    }
    __syncthreads();

    short8v af[4], bf[4];
    #pragma unroll
    for (int mt = 0; mt < 4; ++mt) {
      const int m = wr + mt * 16 + c;
      af[mt] = *reinterpret_cast<const short8v*>(As + ((m * 32 + G * 8) ^ ((m & 7) << 3)));
      const int n = wc + mt * 16 + c;
      bf[mt] = *reinterpret_cast<const short8v*>(Bs + ((n * 32 + G * 8) ^ ((n & 7) << 3)));
    }
    #pragma unroll
    for (int mt = 0; mt < 4; ++mt)
      #pragma unroll
      for (int nt = 0; nt < 4; ++nt)
        acc[mt][nt] = __builtin_amdgcn_mfma_f32_16x16x32_bf16(af[mt], bf[nt], acc[mt][nt], 0, 0, 0);
    __syncthreads();
  }

  float bb[4];
  #pragma unroll
  for (int nt = 0; nt < 4; ++nt) bb[nt] = bias[n0 + wc + nt * 16 + c];

  if (isV) {
    #pragma unroll
    for (int mt = 0; mt < 4; ++mt) {
      #pragma unroll
      for (int nt = 0; nt < 4; ++nt) {
        const int n = wc + nt * 16 + c;
        const int mloc = wr + mt * 16 + G * 4;
        short4v pv;
        #pragma unroll
        for (int r = 0; r < 4; ++r) pv[r] = (short)f2bf(acc[mt][nt][r] + bb[nt]);
        *reinterpret_cast<short4v*>(smem + n * 136 + mloc) = pv;
      }
    }
    __syncthreads();
    const int bb2 = m0 >> 12;
    const int ml0 = m0 & (LSEQ - 1);
    #pragma unroll
    for (int uu = 0; uu < 8; ++uu) {
      const int u = uu * 256 + tid;
      const int n = u >> 4, kg = u & 15;
      short8v vvv = *reinterpret_cast<const short8v*>(smem + n * 136 + kg * 8);
      const int h = (n0 + n) >> 6, d = (n0 + n) & 63;
      *reinterpret_cast<short8v*>(
          VgT + ((size_t)((bb2 << 4) + h) * HD + d) * LSEQ + ml0 + kg * 8) = vvv;
    }
  } else {
    #pragma unroll
    for (int mt = 0; mt < 4; ++mt) {
      #pragma unroll
      for (int nt = 0; nt < 4; ++nt) {
        const int n = n0 + wc + nt * 16 + c;
        const int h = n >> 6, d = n & 63;
        #pragma unroll
        for (int r = 0; r < 4; ++r) {
          const int m = m0 + wr + mt * 16 + G * 4 + r;
          const int b = m >> 12, l = m & (LSEQ - 1);
          Kb[((size_t)((b << 4) + h) * LSEQ + l) * HD + d] = f2bf(acc[mt][nt][r] + bb[nt]);
        }
      }
    }
  }
}

// ---------------------------------------------------------------------------
// Fused projection: by(+y_off) < 8 -> Q-split; 8..15 -> V; >=16 -> K.
// ---------------------------------------------------------------------------
__global__ __launch_bounds__(256) void gemm_proj(
    const u16* __restrict__ X1, const u16* __restrict__ X2, const u16* __restrict__ X3,
    const u16* __restrict__ W1, const u16* __restrict__ W2, const u16* __restrict__ W3,
    const u16* __restrict__ Wkb, const u16* __restrict__ Wvb,
    const float* __restrict__ bq, const float* __restrict__ bk, const float* __restrict__ bv,
    float* __restrict__ Qb, float* __restrict__ norms,
    u16* __restrict__ Kb, u16* __restrict__ VgT, int y_off)
{
  __shared__ __align__(16) u16 smem[24576];   // 48 KB union
  const int by = blockIdx.y + y_off;
  const int bx = blockIdx.x;
  if (by < 8) {
    proj_q_body(smem, X1, X2, X3, W1, W2, W3, bq, Qb, norms, bx, by);
  } else if (by < 16) {
    proj_kv_body(smem, X1, Wvb, bv, Kb, VgT, true, bx, by - 8);
  } else {
    proj_kv_body(smem, X1, Wkb, bk, Kb, VgT, false, bx, by - 16);
  }
}

// ---------------------------------------------------------------------------
// Output GEMM: out = O1b(bf16) @ Wob^T + bo, fp32 row-major out.
// ---------------------------------------------------------------------------
__global__ __launch_bounds__(256) void gemm_out(
    const u16* __restrict__ Xb, const u16* __restrict__ Wb,
    const float* __restrict__ bias, float* __restrict__ Y)
{
  __shared__ u16 As[128 * 32];
  __shared__ u16 Bs[128 * 32];
  const int tid = threadIdx.x;
  const int m0 = blockIdx.x * 128, n0 = blockIdx.y * 128;
  const int wid = tid >> 6, lane = tid & 63;
  const int wr = (wid >> 1) * 64, wc = (wid & 1) * 64;
  const int c = lane & 15, G = lane >> 4;

  int Rr[2], Cr[2];
  #pragma unroll
  for (int rr = 0; rr < 2; ++rr) inv_swz((tid + rr * 256) * 8, Rr[rr], Cr[rr]);

  f32x4 acc[4][4];
  #pragma unroll
  for (int mt = 0; mt < 4; ++mt)
    #pragma unroll
    for (int nt = 0; nt < 4; ++nt)
      acc[mt][nt] = (f32x4){0.f, 0.f, 0.f, 0.f};

  for (int k0 = 0; k0 < DM; k0 += 32) {
    #pragma unroll
    for (int rr = 0; rr < 2; ++rr) {
      const size_t goA = (size_t)(m0 + Rr[rr]) * DM + k0 + Cr[rr] * 8;
      const size_t goB = (size_t)(n0 + Rr[rr]) * DM + k0 + Cr[rr] * 8;
      const int lb = wid * 512 + rr * 2048;
      gl16(Xb + goA, As + lb);
      gl16(Wb + goB, Bs + lb);
    }
    __syncthreads();

    short8v af[4], bf[4];
    #pragma unroll
    for (int mt = 0; mt < 4; ++mt) {
      const int m = wr + mt * 16 + c;
      af[mt] = *reinterpret_cast<const short8v*>(As + ((m * 32 + G * 8) ^ ((m & 7) << 3)));
      const int n = wc + mt * 16 + c;
      bf[mt] = *reinterpret_cast<const short8v*>(Bs + ((n * 32 + G * 8) ^ ((n & 7) << 3)));
    }
    #pragma unroll
    for (int mt = 0; mt < 4; ++mt)
      #pragma unroll
      for (int nt = 0; nt < 4; ++nt)
        acc[mt][nt] = __builtin_amdgcn_mfma_f32_16x16x32_bf16(af[mt], bf[nt], acc[mt][nt], 0, 0, 0);
    __syncthreads();
  }

  float bb[4];
  #pragma unroll
  for (int nt = 0; nt < 4; ++nt) bb[nt] = bias[n0 + wc + nt * 16 + c];

  #pragma unroll
  for (int mt = 0; mt < 4; ++mt) {
    #pragma unroll
    for (int nt = 0; nt < 4; ++nt) {
      const int n = n0 + wc + nt * 16 + c;
      #pragma unroll
      for (int r = 0; r < 4; ++r) {
        const int m = m0 + wr + mt * 16 + G * 4 + r;
        Y[(size_t)m * DM + n] = acc[mt][nt][r] + bb[nt];
      }
    }
  }
}

// ---------------------------------------------------------------------------
// Per-bh top-TOPU selection (set only) -- byte-radix select + stable compact.
// ---------------------------------------------------------------------------
__global__ __launch_bounds__(1024) void select_topk(
    const float* __restrict__ norms, int* __restrict__ top_idx)
{
  __shared__ unsigned int keys[LSEQ];
  __shared__ unsigned int hist[256];
  __shared__ unsigned int wsums[16];
  __shared__ unsigned int sh_b, sh_above;

  const int tid = threadIdx.x;
  const int bh = blockIdx.x;

  for (int l = tid; l < LSEQ; l += 1024)
    keys[l] = __float_as_uint(norms[bh * LSEQ + l]);
  __syncthreads();

  unsigned int prefix = 0, rem = TOPU, total_gt = 0;
  for (int shift = 24; shift >= 0; shift -= 8) {
    if (tid < 256) hist[tid] = 0;
    __syncthreads();
    for (int l = tid; l < LSEQ; l += 1024) {
      const unsigned int k = keys[l];
      const bool in = (shift == 24) || ((k >> (shift + 8)) == prefix);
      if (in) atomicAdd(&hist[(k >> shift) & 255], 1);
    }
    __syncthreads();
    if (tid == 0) {
      unsigned int cum = 0; int b = 255;
      for (; b > 0; --b) {
        const unsigned int h = hist[b];
        if (cum + h >= rem) break;
        cum += h;
      }
      sh_b = (unsigned int)b; sh_above = cum;
    }
    __syncthreads();
    prefix = (prefix << 8) | sh_b;
    total_gt += sh_above;
    rem -= sh_above;
    __syncthreads();
  }
  const unsigned int T = prefix;

  const int lane = tid & 63, wv = tid >> 6;
  const int l0 = tid * 4;

  {
    unsigned int flags = 0; int cnt = 0;
    #pragma unroll
    for (int j = 0; j < 4; ++j)
      if (keys[l0 + j] > T) { flags |= 1u << j; ++cnt; }
    int incl = cnt;
    #pragma unroll
    for (int off = 1; off < 64; off <<= 1) {
      int nv = __shfl_up(incl, off);
      if (lane >= off) incl += nv;
    }
    if (lane == 63) wsums[wv] = (unsigned int)incl;
    __syncthreads();
    if (tid == 0) {
      unsigned int run = 0;
      for (int w = 0; w < 16; ++w) { unsigned int t = wsums[w]; wsums[w] = run; run += t; }
    }
    __syncthreads();
    unsigned int pos = wsums[wv] + (unsigned int)(incl - cnt);
    #pragma unroll
    for (int j = 0; j < 4; ++j)
      if (flags & (1u << j)) top_idx[bh * TOPU + (pos++)] = l0 + j;
  }
  __syncthreads();

  {
    unsigned int flags = 0; int cnt = 0;
    #pragma unroll
    for (int j = 0; j < 4; ++j)
      if (keys[l0 + j] == T) { flags |= 1u << j; ++cnt; }
    int incl = cnt;
    #pragma unroll
    for (int off = 1; off < 64; off <<= 1) {
      int nv = __shfl_up(incl, off);
      if (lane >= off) incl += nv;
    }
    if (lane == 63) wsums[wv] = (unsigned int)incl;
    __syncthreads();
    if (tid == 0) {
      unsigned int run = 0;
      for (int w = 0; w < 16; ++w) { unsigned int t = wsums[w]; wsums[w] = run; run += t; }
    }
    __syncthreads();
    unsigned int r0 = wsums[wv] + (unsigned int)(incl - cnt);
    #pragma unroll
    for (int j = 0; j < 4; ++j)
      if (flags & (1u << j)) {
        if (r0 < rem) top_idx[bh * TOPU + total_gt + r0] = l0 + j;
        ++r0;
      }
  }
}

// ---------------------------------------------------------------------------
// MFMA flash attention, split-K x4, bf16 partial O + fp32 (m,lsum).
// Grid 1664 = 8 xcd * 208; each xcd owns 4 bh.
// ---------------------------------------------------------------------------
__global__ __launch_bounds__(256) void attn_mfma(
    const float* __restrict__ Qf, const u16* __restrict__ Kg,
    const u16* __restrict__ VgT, const int* __restrict__ tix,
    u16* __restrict__ OpartB, float* __restrict__ MLpart)
{
  __shared__ u16 Kc[128 * 64];
  __shared__ u16 Vt[64 * 128];
  __shared__ u16 Pt[4][16 * 136];

  const int tid = threadIdx.x;
  const int wid = tid >> 6, lane = tid & 63;
  const int c = lane & 15, G = lane >> 4;

  const int l = blockIdx.x;
  const int grp = l >> 3;                  // 0..207
  const int bh = (grp / 52) * 8 + (l & 7);
  const int rem = grp % 52;
  const int qb = rem >> 2, ks = rem & 3;

  const size_t bhL = (size_t)bh * LSEQ;
  const int rglob = qb * 64 + wid * 16 + c;
  const int rowidx = (rglob < TOPU) ? tix[bh * TOPU + rglob] : -1;

  short8v qf[2];
  #pragma unroll
  for (int kf = 0; kf < 2; ++kf) {
    if (rowidx >= 0) {
      const float* qp = Qf + (bhL + rowidx) * HD + kf * 32 + G * 8;
      const float4 x0 = *reinterpret_cast<const float4*>(qp);
      const float4 x1 = *reinterpret_cast<const float4*>(qp + 4);
      short8v v;
      v[0] = (short)f2bf(x0.x * 0.125f); v[1] = (short)f2bf(x0.y * 0.125f);
      v[2] = (short)f2bf(x0.z * 0.125f); v[3] = (short)f2bf(x0.w * 0.125f);
      v[4] = (short)f2bf(x1.x * 0.125f); v[5] = (short)f2bf(x1.y * 0.125f);
      v[6] = (short)f2bf(x1.z * 0.125f); v[7] = (short)f2bf(x1.w * 0.125f);
      qf[kf] = v;
    } else {
      short8v v;
      #pragma unroll
      for (int j = 0; j < 8; ++j) v[j] = 0;
      qf[kf] = v;
    }
  }

  float m = -1e30f, lsum = 0.f;
  f32x4 oacc[4];
  #pragma unroll
  for (int dt = 0; dt < 4; ++dt) oacc[dt] = (f32x4){0.f, 0.f, 0.f, 0.f};

  const int ko0 = ks * (LSEQ / NSEG);
  const int wbase = (tid & ~63) * 8;
  for (int t = 0; t < LSEQ / NSEG / 128; ++t) {
    const int ko = ko0 + t * 128;
    #pragma unroll
    for (int uu = 0; uu < 4; ++uu) {
      const int S = (uu * 256 + tid) * 8;
      const int key = S >> 6, dgk = ((S >> 3) & 7) ^ (key & 7);
      gl16(Kg + (bhL + ko + key) * HD + dgk * 8, Kc + uu * 2048 + wbase);
      const int d = S >> 7, kgv = ((S >> 3) & 15) ^ (d & 7);
      gl16(VgT + ((size_t)bh * HD + d) * LSEQ + ko + kgv * 8, Vt + uu * 2048 + wbase);
    }
    __syncthreads();

    f32x4 sacc[8];
    __builtin_amdgcn_s_setprio(1);
    #pragma unroll
    for (int kt = 0; kt < 8; ++kt) {
      const int key = kt * 16 + c;
      short8v kb0 = *reinterpret_cast<const short8v*>(
          Kc + key * 64 + (((0 + G) ^ (key & 7)) << 3));
      short8v kb1 = *reinterpret_cast<const short8v*>(
          Kc + key * 64 + (((4 + G) ^ (key & 7)) << 3));
      f32x4 s = (f32x4){0.f, 0.f, 0.f, 0.f};
      s = __builtin_amdgcn_mfma_f32_16x16x32_bf16(kb0, qf[0], s, 0, 0, 0);
      s = __builtin_amdgcn_mfma_f32_16x16x32_bf16(kb1, qf[1], s, 0, 0, 0);
      sacc[kt] = s;
    }
    __builtin_amdgcn_s_setprio(0);

    float smax = -1e30f;
    #pragma unroll
    for (int kt = 0; kt < 8; ++kt) {
      float a0 = fmaxf(sacc[kt][0], sacc[kt][1]);
      float a1 = fmaxf(sacc[kt][2], sacc[kt][3]);
      smax = fmaxf(smax, fmaxf(a0, a1));
    }
    smax = fmaxf(smax, __shfl_xor(smax, 16));
    smax = fmaxf(smax, __shfl_xor(smax, 32));
    const float mnew = fmaxf(m, smax);
    const float corr = __expf(m - mnew);
    float ssum = 0.f;
    #pragma unroll
    for (int kt = 0; kt < 8; ++kt) {
      float p0 = __expf(sacc[kt][0] - mnew);
      float p1 = __expf(sacc[kt][1] - mnew);
      float p2 = __expf(sacc[kt][2] - mnew);
      float p3 = __expf(sacc[kt][3] - mnew);
      ssum += (p0 + p1) + (p2 + p3);
      short4v pv;
      pv[0] = (short)f2bf(p0); pv[1] = (short)f2bf(p1);
      pv[2] = (short)f2bf(p2); pv[3] = (short)f2bf(p3);
      *reinterpret_cast<short4v*>(&Pt[wid][c * 136 + kt * 16 + G * 4]) = pv;
    }
    ssum += __shfl_xor(ssum, 16);
    ssum += __shfl_xor(ssum, 32);
    lsum = lsum * corr + ssum;
    m = mnew;
    #pragma unroll
    for (int dt = 0; dt < 4; ++dt) oacc[dt] *= corr;

    __builtin_amdgcn_s_setprio(1);
    #pragma unroll
    for (int kf = 0; kf < 4; ++kf) {
      short8v pf = *reinterpret_cast<const short8v*>(
          &Pt[wid][c * 136 + kf * 32 + G * 8]);
      #pragma unroll
      for (int dt = 0; dt < 4; ++dt) {
        const int d = dt * 16 + c;
        short8v vf = *reinterpret_cast<const short8v*>(
            Vt + d * 128 + (((kf * 4 + G) ^ (d & 7)) << 3));
        oacc[dt] = __builtin_amdgcn_mfma_f32_16x16x32_bf16(vf, pf, oacc[dt], 0, 0, 0);
      }
    }
    __builtin_amdgcn_s_setprio(0);
    __syncthreads();
  }

  const int q = wid * 16 + c;
  const size_t pb = ((size_t)((bh * 13 + qb) * NSEG + ks)) * 64 + q;
  u16* op = OpartB + pb * 64;
  #pragma unroll
  for (int dt = 0; dt < 4; ++dt) {
    short4v o;
    o[0] = (short)f2bf(oacc[dt][0]); o[1] = (short)f2bf(oacc[dt][1]);
    o[2] = (short)f2bf(oacc[dt][2]); o[3] = (short)f2bf(oacc[dt][3]);
    *reinterpret_cast<short4v*>(op + dt * 16 + G * 4) = o;
  }
  if (G == 0) {
    MLpart[pb * 2]     = m;
    MLpart[pb * 2 + 1] = lsum;
  }
}

// ---------------------------------------------------------------------------
// 4-way split-K combine: O = sum_i Oi*ci / sum_i li*ci, scatter bf16 to O1b.
// ---------------------------------------------------------------------------
__global__ __launch_bounds__(256) void attn_combine(
    const u16* __restrict__ OpartB, const float* __restrict__ MLpart,
    const int* __restrict__ tix, u16* __restrict__ O1b)
{
  const int bq = blockIdx.x;
  const int bh = bq / 13, qb = bq % 13;
  const int tid = threadIdx.x;
  const int q = tid >> 2, dq = (tid & 3) * 16;
  const int rglob = qb * 64 + q;
  if (rglob >= TOPU) return;
  const int rowidx = tix[bh * TOPU + rglob];

  size_t p[NSEG];
  float mi[NSEG], li[NSEG];
  #pragma unroll
  for (int i = 0; i < NSEG; ++i) {
    p[i] = ((size_t)bq * NSEG + i) * 64 + q;
    mi[i] = MLpart[p[i] * 2];
    li[i] = MLpart[p[i] * 2 + 1];
  }
  float mx = fmaxf(fmaxf(mi[0], mi[1]), fmaxf(mi[2], mi[3]));
  float ci[NSEG], lsum = 0.f;
  #pragma unroll
  for (int i = 0; i < NSEG; ++i) { ci[i] = __expf(mi[i] - mx); lsum += li[i] * ci[i]; }
  const float linv = 1.0f / lsum;

  float acc[16];
  #pragma unroll
  for (int j = 0; j < 16; ++j) acc[j] = 0.f;
  #pragma unroll
  for (int i = 0; i < NSEG; ++i) {
    const u16* src = OpartB + p[i] * 64 + dq;
    #pragma unroll
    for (int j = 0; j < 16; ++j) acc[j] += bf2f(src[j]) * ci[i];
  }

  const int b = bh >> 4, h = bh & 15;
  u16* dst = O1b + (size_t)(b * LSEQ + rowidx) * DM + h * HD + dq;
  #pragma unroll
  for (int j0 = 0; j0 < 16; j0 += 4) {
    short4v o;
    #pragma unroll
    for (int j = 0; j < 4; ++j) o[j] = (short)f2bf(acc[j0 + j] * linv);
    *reinterpret_cast<short4v*>(dst + j0) = o;
  }
}

// ---------------------------------------------------------------------------
extern "C" void kernel_launch(void* const* d_in, const int* in_sizes, int n_in,
                              void* d_out, int out_size, void* d_ws, size_t ws_size,
                              hipStream_t stream) {
  const float* x  = (const float*)d_in[0];
  const float* Wq = (const float*)d_in[1];
  const float* bq = (const float*)d_in[2];
  const float* Wk = (const float*)d_in[3];
  const float* bk = (const float*)d_in[4];
  const float* Wv = (const float*)d_in[5];
  const float* bv = (const float*)d_in[6];
  const float* Wo = (const float*)d_in[7];
  const float* bo = (const float*)d_in[8];
  float* out = (float*)d_out;

  char* w = (char*)d_ws;
  float* Qb = (float*)w;  w += (size_t)BHT * LSEQ * HD * 4;    // 32 MB
  u16* x1   = (u16*)w;    w += (size_t)MROWS * DM * 2;         // 16 MB -> OpartB/ML
  u16* x2   = (u16*)w;    w += (size_t)MROWS * DM * 2;         // 16 MB -> O1b
  u16* x3   = (u16*)w;    w += (size_t)MROWS * DM * 2;         // 16 MB (-> Kb fallback)
  u16* VgT  = (u16*)w;    w += (size_t)BHT * HD * LSEQ * 2;    // 16 MB
  u16* Wkb  = (u16*)w;    w += (size_t)DM * DM * 2;            // 2 MB
  u16* Wvb  = (u16*)w;    w += (size_t)DM * DM * 2;
  u16* Wob  = (u16*)w;    w += (size_t)DM * DM * 2;
  u16* wq1  = (u16*)w;    w += (size_t)DM * DM * 2;
  u16* wq2  = (u16*)w;    w += (size_t)DM * DM * 2;            // -> tix
  u16* wq3  = (u16*)w;    w += (size_t)DM * DM * 2;
  float* norms = (float*)w; w += (size_t)BHT * LSEQ * 4;       // 512 KB
  u16* Kb_ext = (u16*)w;  w += (size_t)BHT * LSEQ * HD * 2;    // 16 MB (if room)

  const bool fusedK = ws_size >= (size_t)(w - (char*)d_ws);
  u16* Kb = fusedK ? Kb_ext : x3;   // x3-alias only safe when K runs AFTER Q

  u16*   O1b    = x2;
  int*   tix    = (int*)wq2;
  u16*   OpartB = x1;               // dead after gemm_proj
  const int NPB = BHT * 13 * NSEG * 64;       // partial rows = 106496
  float* MLpart = (float*)(OpartB + (size_t)NPB * 64);  // 13.6 + 0.85 MB <= 16

  prep_all<<<6144, 256, 0, stream>>>(x, Wq, Wk, Wv, Wo,
                                     x1, x2, x3, wq1, wq2, wq3, Wkb, Wvb, Wob);

  if (fusedK) {
    gemm_proj<<<dim3(64, 24), 256, 0, stream>>>(
        x1, x2, x3, wq1, wq2, wq3, Wkb, Wvb, bq, bk, bv, Qb, norms, Kb, VgT, 0);
  } else {
    gemm_proj<<<dim3(64, 16), 256, 0, stream>>>(
        x1, x2, x3, wq1, wq2, wq3, Wkb, Wvb, bq, bk, bv, Qb, norms, Kb, VgT, 0);
    gemm_proj<<<dim3(64, 8), 256, 0, stream>>>(
        x1, x2, x3, wq1, wq2, wq3, Wkb, Wvb, bq, bk, bv, Qb, norms, Kb, VgT, 16);
  }

  select_topk<<<BHT, 1024, 0, stream>>>(norms, tix);

  hipMemsetAsync(O1b, 0, (size_t)MROWS * DM * 2, stream);

  attn_mfma<<<BHT * 13 * NSEG, 256, 0, stream>>>(Qb, Kb, VgT, tix, OpartB, MLpart);
  attn_combine<<<BHT * 13, 256, 0, stream>>>(OpartB, MLpart, tix, O1b);

  gemm_out<<<dim3(MROWS / 128, DM / 128), 256, 0, stream>>>(O1b, Wob, bo, out);
}